// Round 16
// baseline (105.279 us; speedup 1.0000x reference)
//
#include <hip/hip_runtime.h>

#define N_NODES 50000
#define N_EDGES 800000
#define NB_SCAN 196   // ceil(N_NODES/256)

typedef _Float16 f16x8 __attribute__((ext_vector_type(8)));
typedef _Float16 f16x4 __attribute__((ext_vector_type(4)));
typedef float    f32x4 __attribute__((ext_vector_type(4)));

__device__ __forceinline__ unsigned f16bits(float f) {
    const _Float16 h = (_Float16)f;
    return (unsigned)*(const unsigned short*)&h;
}
__device__ __forceinline__ float f16val(unsigned u) {
    const unsigned short us = (unsigned short)u;
    return (float)*(const _Float16*)&us;
}

// ---------------- K0: x -> fp16 copy; zero counts; blocks 0-7 also pack W frags
__global__ void xh_kernel(const float* __restrict__ x, _Float16* __restrict__ xh,
                          int* __restrict__ counts,
                          const float* __restrict__ g, const float* __restrict__ root,
                          _Float16* __restrict__ wfrag) {
    const int i = blockIdx.x * 256 + threadIdx.x;
    if (i < N_NODES) counts[i] = 0;
    if (i < 2048) {   // fused wprep (blocks 0-7)
        const int lane = i & 63;
        const int cc   = (i >> 6) & 3;
        const int kc   = i >> 8;
        const int d     = cc * 16 + (lane & 15);
        const int kbase = kc * 32 + (lane >> 4) * 8;
        f16x8 v;
#pragma unroll
        for (int q = 0; q < 8; ++q) {
            const int k = kbase + q;
            const float w = (k < 192) ? g[(k & 63) * 192 + (k >> 6) * 64 + d]
                                      : root[(k - 192) * 64 + d];
            v[q] = (_Float16)w;
        }
        *(f16x8*)&wfrag[(size_t)i * 8] = v;
    }
    if (i >= N_NODES * 16) return;
    const float4 v = *(const float4*)&x[(size_t)i * 4];
    f16x4 h;
    h[0] = (_Float16)v.x; h[1] = (_Float16)v.y;
    h[2] = (_Float16)v.z; h[3] = (_Float16)v.w;
    *(f16x4*)&xh[(size_t)i * 4] = h;
}

// ---------------- K1: histogram of destination degrees + rank assignment
__global__ void hist_kernel(const int* __restrict__ ei, int* __restrict__ counts,
                            int* __restrict__ rank) {
    int e = blockIdx.x * 256 + threadIdx.x;
    if (e < N_EDGES) rank[e] = atomicAdd(&counts[ei[N_EDGES + e]], 1);
}

// ---------------- K2a: per-block sums of counts
__global__ void scanA_kernel(const int* __restrict__ counts, int* __restrict__ bsum) {
    __shared__ int s[256];
    int i = blockIdx.x * 256 + threadIdx.x;
    s[threadIdx.x] = (i < N_NODES) ? counts[i] : 0;
    __syncthreads();
    for (int d = 128; d > 0; d >>= 1) {
        if (threadIdx.x < d) s[threadIdx.x] += s[threadIdx.x + d];
        __syncthreads();
    }
    if (threadIdx.x == 0) bsum[blockIdx.x] = s[0];
}

// ---------------- K2c: per-element exclusive offsets (block prefix derived in-kernel)
__global__ void scanC_kernel(const int* __restrict__ counts, const int* __restrict__ bsum,
                             int* __restrict__ off) {
    __shared__ int s[256];
    __shared__ int rs[256];
    const int tid = threadIdx.x;
    rs[tid] = (tid < NB_SCAN && tid < blockIdx.x) ? bsum[tid] : 0;
    __syncthreads();
    for (int d = 128; d > 0; d >>= 1) {
        if (tid < d) rs[tid] += rs[tid + d];
        __syncthreads();
    }
    const int boff = rs[0];
    const int i = blockIdx.x * 256 + tid;
    const int v = (i < N_NODES) ? counts[i] : 0;
    s[tid] = v;
    __syncthreads();
    for (int d = 1; d < 256; d <<= 1) {
        int t = (tid >= d) ? s[tid - d] : 0;
        __syncthreads();
        s[tid] += t;
        __syncthreads();
    }
    const int excl = s[tid] - v + boff;
    if (i < N_NODES) off[i] = excl;
    if (i == 0) off[N_NODES] = N_EDGES;
}

// ---------------- K3: scatter 4B {src:u16, u:q16} records to CSR positions
__global__ void scatter_kernel(const int* __restrict__ ei,
                               const float* __restrict__ pseudo,
                               const int* __restrict__ off,
                               const int* __restrict__ rank,
                               unsigned* __restrict__ packed) {
    int e = blockIdx.x * 256 + threadIdx.x;
    if (e >= N_EDGES) return;
    const int s  = ei[e];
    const int dd = ei[N_EDGES + e];
    const unsigned uq = __float2uint_rn(__saturatef(pseudo[e]) * 65535.0f);
    const int pos = off[dd] + rank[e];
    packed[pos] = (unsigned)s | (uq << 16);
}

// ---------------- K4: FUSED aggregate + MFMA GEMM + epilogue.
// Block = 4 waves = 16 nodes (one MFMA A-tile). Latency pipeline: block's 17
// off values preloaded to LDS; each wave issues its 4 nodes' record loads
// UPFRONT (independent), then processes nodes with 8-deep gather unroll
// (16 edges in flight). Split-wave: lanes 0-31 even edges, 32-63 odd; 2
// features/lane. Then 4 waves each compute one 16x16 col-tile via 8 MFMAs
// + bias + residual + silu.
#define MFMA16(a, b, c) __builtin_amdgcn_mfma_f32_16x16x32_f16(a, b, c, 0, 0, 0)
__global__ __launch_bounds__(256)
void agg_gemm_kernel(const _Float16* __restrict__ xh,
                     const unsigned* __restrict__ packed,
                     const int* __restrict__ off,
                     const float* __restrict__ mu,
                     const float* __restrict__ sigma,
                     const _Float16* __restrict__ wfrag,
                     const float* __restrict__ bias,
                     float* __restrict__ out) {
    __shared__ _Float16 sA[16][264];   // 8.4 KB
    __shared__ int sOff[17];
    const int tid  = threadIdx.x;
    const int lane = tid & 63;
    const int l32  = lane & 31;
    const int half = lane >> 5;
    const int wid  = tid >> 6;
    if (tid < 17) sOff[tid] = off[blockIdx.x * 16 + tid];
    __syncthreads();
    const float mu0 = mu[0], mu1 = mu[1], mu2 = mu[2];
    const float s0 = sigma[0], s1 = sigma[1], s2 = sigma[2];
    const float c0 = -0.5f / (1e-14f + s0 * s0);
    const float c1 = -0.5f / (1e-14f + s1 * s1);
    const float c2 = -0.5f / (1e-14f + s2 * s2);

    const int o0 = sOff[wid * 4 + 0];
    const int o1 = sOff[wid * 4 + 1];
    const int o2 = sOff[wid * 4 + 2];
    const int o3 = sOff[wid * 4 + 3];
    const int o4 = sOff[wid * 4 + 4];
    const int d0 = o1 - o0, d1 = o2 - o1, d2 = o3 - o2, d3 = o4 - o3;
    // issue all 4 record loads upfront (independent, in flight together)
    unsigned rec0 = 0, rec1 = 0, rec2 = 0, rec3 = 0;
    if (lane < d0) rec0 = packed[o0 + lane];
    if (lane < d1) rec1 = packed[o1 + lane];
    if (lane < d2) rec2 = packed[o2 + lane];
    if (lane < d3) rec3 = packed[o3 + lane];

#define GATH(q)                                                                   \
    const unsigned wae##q = (unsigned)__shfl((int)wa, 2 * (j + q) + half);        \
    const unsigned wbe##q = (unsigned)__shfl((int)wb, 2 * (j + q) + half);        \
    const unsigned xp##q = *(const unsigned*)&xh[(size_t)(wbe##q & 0xFFFFu) * 64 + l32 * 2];
#define ACCU(q)                                                                   \
    {                                                                             \
        const float xlo = f16val(xp##q & 0xFFFFu), xhi = f16val(xp##q >> 16);     \
        const float w0 = f16val(wae##q & 0xFFFFu);                                \
        const float w1 = f16val(wae##q >> 16);                                    \
        const float w2 = f16val(wbe##q >> 16);                                    \
        a0lo += w0 * xlo; a0hi += w0 * xhi;                                       \
        a1lo += w1 * xlo; a1hi += w1 * xhi;                                       \
        a2lo += w2 * xlo; a2hi += w2 * xhi;                                       \
    }

    auto process = [&](int start, int deg, unsigned rec, int lrow) {
        float a0lo = 0.f, a0hi = 0.f, a1lo = 0.f, a1hi = 0.f, a2lo = 0.f, a2hi = 0.f;
        // chunk 0 from the preloaded record
        {
            const int nrec = min(64, deg);
            const float u = (float)(rec >> 16) * (1.0f / 65535.0f);
            const float e0 = u - mu0, e1 = u - mu1, e2 = u - mu2;
            unsigned wa = f16bits(__expf(c0 * e0 * e0))
                        | (f16bits(__expf(c1 * e1 * e1)) << 16);
            unsigned wb = (rec & 0xFFFFu)
                        | (f16bits(__expf(c2 * e2 * e2)) << 16);
            if (lane >= nrec) { wa = 0u; wb = 0u; }
            const int steps = (nrec + 1) >> 1;
            int j = 0;
            for (; j + 8 <= steps; j += 8) {
                GATH(0) GATH(1) GATH(2) GATH(3) GATH(4) GATH(5) GATH(6) GATH(7)
                ACCU(0) ACCU(1) ACCU(2) ACCU(3) ACCU(4) ACCU(5) ACCU(6) ACCU(7)
            }
            for (; j + 4 <= steps; j += 4) {
                GATH(0) GATH(1) GATH(2) GATH(3)
                ACCU(0) ACCU(1) ACCU(2) ACCU(3)
            }
            for (; j < steps; ++j) {
                GATH(0)
                ACCU(0)
            }
        }
        // rare tail: degree > 64
        for (int base = start + 64; base < start + deg; base += 64) {
            const int nrec = min(64, start + deg - base);
            unsigned r2 = 0;
            if (lane < nrec) r2 = packed[base + lane];
            const float u = (float)(r2 >> 16) * (1.0f / 65535.0f);
            const float e0 = u - mu0, e1 = u - mu1, e2 = u - mu2;
            unsigned wa = f16bits(__expf(c0 * e0 * e0))
                        | (f16bits(__expf(c1 * e1 * e1)) << 16);
            unsigned wb = (r2 & 0xFFFFu)
                        | (f16bits(__expf(c2 * e2 * e2)) << 16);
            if (lane >= nrec) { wa = 0u; wb = 0u; }
            const int steps = (nrec + 1) >> 1;
            int j = 0;
            for (; j + 8 <= steps; j += 8) {
                GATH(0) GATH(1) GATH(2) GATH(3) GATH(4) GATH(5) GATH(6) GATH(7)
                ACCU(0) ACCU(1) ACCU(2) ACCU(3) ACCU(4) ACCU(5) ACCU(6) ACCU(7)
            }
            for (; j + 4 <= steps; j += 4) {
                GATH(0) GATH(1) GATH(2) GATH(3)
                ACCU(0) ACCU(1) ACCU(2) ACCU(3)
            }
            for (; j < steps; ++j) {
                GATH(0)
                ACCU(0)
            }
        }
        // combine halves, write LDS A-tile row
        a0lo += __shfl_xor(a0lo, 32); a0hi += __shfl_xor(a0hi, 32);
        a1lo += __shfl_xor(a1lo, 32); a1hi += __shfl_xor(a1hi, 32);
        a2lo += __shfl_xor(a2lo, 32); a2hi += __shfl_xor(a2hi, 32);
        const float inv = 1.0f / fmaxf((float)deg, 1.0f);
        const int node = blockIdx.x * 16 + lrow;
        if (half == 0) {
            *(unsigned*)&sA[lrow][2 * l32]      = f16bits(a0lo * inv) | (f16bits(a0hi * inv) << 16);
            *(unsigned*)&sA[lrow][64 + 2 * l32] = f16bits(a1lo * inv) | (f16bits(a1hi * inv) << 16);
        } else {
            *(unsigned*)&sA[lrow][128 + 2 * l32] = f16bits(a2lo * inv) | (f16bits(a2hi * inv) << 16);
            *(unsigned*)&sA[lrow][192 + 2 * l32] = *(const unsigned*)&xh[(size_t)node * 64 + 2 * l32];
        }
    };
    process(o0, d0, rec0, wid * 4 + 0);
    process(o1, d1, rec1, wid * 4 + 1);
    process(o2, d2, rec2, wid * 4 + 2);
    process(o3, d3, rec3, wid * 4 + 3);
#undef GATH
#undef ACCU
    __syncthreads();

    // GEMM phase: wave `wid` computes col-tile c = wid (16 rows x 16 cols)
    const int r  = lane & 15;       // A row
    const int kq = lane >> 4;       // k-quarter
    const f16x8 af0 = *(const f16x8*)&sA[r][0 * 32 + kq * 8];
    const f16x8 af1 = *(const f16x8*)&sA[r][1 * 32 + kq * 8];
    const f16x8 af2 = *(const f16x8*)&sA[r][2 * 32 + kq * 8];
    const f16x8 af3 = *(const f16x8*)&sA[r][3 * 32 + kq * 8];
    const f16x8 af4 = *(const f16x8*)&sA[r][4 * 32 + kq * 8];
    const f16x8 af5 = *(const f16x8*)&sA[r][5 * 32 + kq * 8];
    const f16x8 af6 = *(const f16x8*)&sA[r][6 * 32 + kq * 8];
    const f16x8 af7 = *(const f16x8*)&sA[r][7 * 32 + kq * 8];
    const f16x8 bf0 = *(const f16x8*)&wfrag[(size_t)((0 * 4 + wid) * 64 + lane) * 8];
    const f16x8 bf1 = *(const f16x8*)&wfrag[(size_t)((1 * 4 + wid) * 64 + lane) * 8];
    const f16x8 bf2 = *(const f16x8*)&wfrag[(size_t)((2 * 4 + wid) * 64 + lane) * 8];
    const f16x8 bf3 = *(const f16x8*)&wfrag[(size_t)((3 * 4 + wid) * 64 + lane) * 8];
    const f16x8 bf4 = *(const f16x8*)&wfrag[(size_t)((4 * 4 + wid) * 64 + lane) * 8];
    const f16x8 bf5 = *(const f16x8*)&wfrag[(size_t)((5 * 4 + wid) * 64 + lane) * 8];
    const f16x8 bf6 = *(const f16x8*)&wfrag[(size_t)((6 * 4 + wid) * 64 + lane) * 8];
    const f16x8 bf7 = *(const f16x8*)&wfrag[(size_t)((7 * 4 + wid) * 64 + lane) * 8];

    f32x4 acc = {0.f, 0.f, 0.f, 0.f};
    acc = MFMA16(af0, bf0, acc);
    acc = MFMA16(af1, bf1, acc);
    acc = MFMA16(af2, bf2, acc);
    acc = MFMA16(af3, bf3, acc);
    acc = MFMA16(af4, bf4, acc);
    acc = MFMA16(af5, bf5, acc);
    acc = MFMA16(af6, bf6, acc);
    acc = MFMA16(af7, bf7, acc);

    // epilogue: D col=lane&15, row=(lane>>4)*4+reg
    const int col = wid * 16 + r;
    const float bv = bias[col];
    const int lrow0 = (lane >> 4) * 4;
#pragma unroll
    for (int q = 0; q < 4; ++q) {
        const int lr = lrow0 + q;
        const float res = (float)sA[lr][192 + col];
        const float v = acc[q] + bv + res;
        out[(size_t)(blockIdx.x * 16 + lr) * 64 + col] = v / (1.0f + expf(-v));
    }
}

extern "C" void kernel_launch(void* const* d_in, const int* in_sizes, int n_in,
                              void* d_out, int out_size, void* d_ws, size_t ws_size,
                              hipStream_t stream) {
    const float* x     = (const float*)d_in[0];
    const int*   ei    = (const int*)d_in[1];
    const float* ea    = (const float*)d_in[2];
    const float* g     = (const float*)d_in[3];
    const float* mu    = (const float*)d_in[4];
    const float* sigma = (const float*)d_in[5];
    const float* root  = (const float*)d_in[6];
    const float* bias  = (const float*)d_in[7];
    float* out = (float*)d_out;

    char* ws = (char*)d_ws;
    const size_t xh_bytes     = (size_t)N_NODES * 64 * sizeof(_Float16);  //  6.4 MB
    const size_t packed_bytes = (size_t)N_EDGES * sizeof(unsigned);       //  3.2 MB
    const size_t rank_bytes   = (size_t)N_EDGES * sizeof(int);            //  3.2 MB
    const size_t wfrag_bytes  = (size_t)2048 * 8 * sizeof(_Float16);      //  32 KB
    _Float16* xh     = (_Float16*)ws;
    unsigned* packed = (unsigned*)(ws + xh_bytes);
    int*      rank   = (int*)(ws + xh_bytes + packed_bytes);
    _Float16* wfrag  = (_Float16*)(ws + xh_bytes + packed_bytes + rank_bytes);
    int* counts = (int*)(ws + xh_bytes + packed_bytes + rank_bytes + wfrag_bytes);
    int* off    = counts + N_NODES;           // N_NODES+1 entries
    int* bsum   = off + N_NODES + 1;

    xh_kernel<<<(N_NODES * 16 + 255) / 256, 256, 0, stream>>>(x, xh, counts, g, root, wfrag);
    hist_kernel<<<(N_EDGES + 255) / 256, 256, 0, stream>>>(ei, counts, rank);
    scanA_kernel<<<NB_SCAN, 256, 0, stream>>>(counts, bsum);
    scanC_kernel<<<NB_SCAN, 256, 0, stream>>>(counts, bsum, off);
    scatter_kernel<<<(N_EDGES + 255) / 256, 256, 0, stream>>>(ei, ea, off, rank, packed);
    agg_gemm_kernel<<<N_NODES / 16, 256, 0, stream>>>(xh, packed, off, mu, sigma, wfrag, bias, out);
}

// Round 17
// 99.739 us; speedup vs baseline: 1.0555x; 1.0555x over previous
//
#include <hip/hip_runtime.h>

#define N_NODES 50000
#define N_EDGES 800000
#define NB_SCAN 196   // ceil(N_NODES/256)

typedef _Float16 f16x8 __attribute__((ext_vector_type(8)));
typedef _Float16 f16x4 __attribute__((ext_vector_type(4)));
typedef float    f32x4 __attribute__((ext_vector_type(4)));

__device__ __forceinline__ unsigned f16bits(float f) {
    const _Float16 h = (_Float16)f;
    return (unsigned)*(const unsigned short*)&h;
}
__device__ __forceinline__ float f16val(unsigned u) {
    const unsigned short us = (unsigned short)u;
    return (float)*(const _Float16*)&us;
}

// ---------------- K0: x -> fp16 copy; zero counts; blocks 0-7 also pack W frags
__global__ void xh_kernel(const float* __restrict__ x, _Float16* __restrict__ xh,
                          int* __restrict__ counts,
                          const float* __restrict__ g, const float* __restrict__ root,
                          _Float16* __restrict__ wfrag) {
    const int i = blockIdx.x * 256 + threadIdx.x;
    if (i < N_NODES) counts[i] = 0;
    if (i < 2048) {   // fused wprep (blocks 0-7)
        const int lane = i & 63;
        const int cc   = (i >> 6) & 3;
        const int kc   = i >> 8;
        const int d     = cc * 16 + (lane & 15);
        const int kbase = kc * 32 + (lane >> 4) * 8;
        f16x8 v;
#pragma unroll
        for (int q = 0; q < 8; ++q) {
            const int k = kbase + q;
            const float w = (k < 192) ? g[(k & 63) * 192 + (k >> 6) * 64 + d]
                                      : root[(k - 192) * 64 + d];
            v[q] = (_Float16)w;
        }
        *(f16x8*)&wfrag[(size_t)i * 8] = v;
    }
    if (i >= N_NODES * 16) return;
    const float4 v = *(const float4*)&x[(size_t)i * 4];
    f16x4 h;
    h[0] = (_Float16)v.x; h[1] = (_Float16)v.y;
    h[2] = (_Float16)v.z; h[3] = (_Float16)v.w;
    *(f16x4*)&xh[(size_t)i * 4] = h;
}

// ---------------- K1: histogram of destination degrees + rank assignment
__global__ void hist_kernel(const int* __restrict__ ei, int* __restrict__ counts,
                            int* __restrict__ rank) {
    int e = blockIdx.x * 256 + threadIdx.x;
    if (e < N_EDGES) rank[e] = atomicAdd(&counts[ei[N_EDGES + e]], 1);
}

// ---------------- K2a: per-block sums of counts
__global__ void scanA_kernel(const int* __restrict__ counts, int* __restrict__ bsum) {
    __shared__ int s[256];
    int i = blockIdx.x * 256 + threadIdx.x;
    s[threadIdx.x] = (i < N_NODES) ? counts[i] : 0;
    __syncthreads();
    for (int d = 128; d > 0; d >>= 1) {
        if (threadIdx.x < d) s[threadIdx.x] += s[threadIdx.x + d];
        __syncthreads();
    }
    if (threadIdx.x == 0) bsum[blockIdx.x] = s[0];
}

// ---------------- K2c: per-element exclusive offsets (block prefix derived in-kernel)
__global__ void scanC_kernel(const int* __restrict__ counts, const int* __restrict__ bsum,
                             int* __restrict__ off) {
    __shared__ int s[256];
    __shared__ int rs[256];
    const int tid = threadIdx.x;
    rs[tid] = (tid < NB_SCAN && tid < blockIdx.x) ? bsum[tid] : 0;
    __syncthreads();
    for (int d = 128; d > 0; d >>= 1) {
        if (tid < d) rs[tid] += rs[tid + d];
        __syncthreads();
    }
    const int boff = rs[0];
    const int i = blockIdx.x * 256 + tid;
    const int v = (i < N_NODES) ? counts[i] : 0;
    s[tid] = v;
    __syncthreads();
    for (int d = 1; d < 256; d <<= 1) {
        int t = (tid >= d) ? s[tid - d] : 0;
        __syncthreads();
        s[tid] += t;
        __syncthreads();
    }
    const int excl = s[tid] - v + boff;
    if (i < N_NODES) off[i] = excl;
    if (i == 0) off[N_NODES] = N_EDGES;
}

// ---------------- K3: scatter 4B {src:u16, u:q16} records to CSR positions
__global__ void scatter_kernel(const int* __restrict__ ei,
                               const float* __restrict__ pseudo,
                               const int* __restrict__ off,
                               const int* __restrict__ rank,
                               unsigned* __restrict__ packed) {
    int e = blockIdx.x * 256 + threadIdx.x;
    if (e >= N_EDGES) return;
    const int s  = ei[e];
    const int dd = ei[N_EDGES + e];
    const unsigned uq = __float2uint_rn(__saturatef(pseudo[e]) * 65535.0f);
    const int pos = off[dd] + rank[e];
    packed[pos] = (unsigned)s | (uq << 16);
}

// ---------------- K4: FUSED aggregate + MFMA GEMM + epilogue (round-15 best).
#define MFMA16(a, b, c) __builtin_amdgcn_mfma_f32_16x16x32_f16(a, b, c, 0, 0, 0)
__global__ __launch_bounds__(256)
void agg_gemm_kernel(const _Float16* __restrict__ xh,
                     const unsigned* __restrict__ packed,
                     const int* __restrict__ off,
                     const float* __restrict__ mu,
                     const float* __restrict__ sigma,
                     const _Float16* __restrict__ wfrag,
                     const float* __restrict__ bias,
                     float* __restrict__ out) {
    __shared__ _Float16 sA[16][264];   // 8.4 KB
    const int tid  = threadIdx.x;
    const int lane = tid & 63;
    const int l32  = lane & 31;
    const int half = lane >> 5;
    const int wid  = tid >> 6;
    const float mu0 = mu[0], mu1 = mu[1], mu2 = mu[2];
    const float s0 = sigma[0], s1 = sigma[1], s2 = sigma[2];
    const float c0 = -0.5f / (1e-14f + s0 * s0);
    const float c1 = -0.5f / (1e-14f + s1 * s1);
    const float c2 = -0.5f / (1e-14f + s2 * s2);

#define GATH(q)                                                                   \
    const unsigned wae##q = (unsigned)__shfl((int)wa, 2 * (j + q) + half);        \
    const unsigned wbe##q = (unsigned)__shfl((int)wb, 2 * (j + q) + half);        \
    const unsigned xp##q = *(const unsigned*)&xh[(size_t)(wbe##q & 0xFFFFu) * 64 + l32 * 2];
#define ACCU(q)                                                                   \
    {                                                                             \
        const float xlo = f16val(xp##q & 0xFFFFu), xhi = f16val(xp##q >> 16);     \
        const float w0 = f16val(wae##q & 0xFFFFu);                                \
        const float w1 = f16val(wae##q >> 16);                                    \
        const float w2 = f16val(wbe##q >> 16);                                    \
        a0lo += w0 * xlo; a0hi += w0 * xhi;                                       \
        a1lo += w1 * xlo; a1hi += w1 * xhi;                                       \
        a2lo += w2 * xlo; a2hi += w2 * xhi;                                       \
    }

#pragma unroll 1
    for (int i = 0; i < 4; ++i) {
        const int lrow = wid * 4 + i;
        const int node = blockIdx.x * 16 + lrow;   // 50000 = 3125*16, always valid
        const int start = off[node], end = off[node + 1];
        float a0lo = 0.f, a0hi = 0.f, a1lo = 0.f, a1hi = 0.f, a2lo = 0.f, a2hi = 0.f;
        for (int base = start; base < end; base += 64) {
            const int nrec = min(64, end - base);
            unsigned rec = 0;
            if (lane < nrec) rec = packed[base + lane];   // coalesced 4B/lane
            const float u = (float)(rec >> 16) * (1.0f / 65535.0f);
            const float d0 = u - mu0, d1 = u - mu1, d2 = u - mu2;
            unsigned wa = f16bits(__expf(c0 * d0 * d0))
                        | (f16bits(__expf(c1 * d1 * d1)) << 16);
            unsigned wb = (rec & 0xFFFFu)
                        | (f16bits(__expf(c2 * d2 * d2)) << 16);
            if (lane >= nrec) { wa = 0u; wb = 0u; }
            const int steps = (nrec + 1) >> 1;
            int j = 0;
            for (; j + 4 <= steps; j += 4) {
                GATH(0) GATH(1) GATH(2) GATH(3)
                ACCU(0) ACCU(1) ACCU(2) ACCU(3)
            }
            for (; j < steps; ++j) {
                GATH(0)
                ACCU(0)
            }
        }
        // combine halves, write LDS A-tile row
        a0lo += __shfl_xor(a0lo, 32); a0hi += __shfl_xor(a0hi, 32);
        a1lo += __shfl_xor(a1lo, 32); a1hi += __shfl_xor(a1hi, 32);
        a2lo += __shfl_xor(a2lo, 32); a2hi += __shfl_xor(a2hi, 32);
        const float inv = 1.0f / fmaxf((float)(end - start), 1.0f);
        if (half == 0) {
            *(unsigned*)&sA[lrow][2 * l32]      = f16bits(a0lo * inv) | (f16bits(a0hi * inv) << 16);
            *(unsigned*)&sA[lrow][64 + 2 * l32] = f16bits(a1lo * inv) | (f16bits(a1hi * inv) << 16);
        } else {
            *(unsigned*)&sA[lrow][128 + 2 * l32] = f16bits(a2lo * inv) | (f16bits(a2hi * inv) << 16);
            *(unsigned*)&sA[lrow][192 + 2 * l32] = *(const unsigned*)&xh[(size_t)node * 64 + 2 * l32];
        }
    }
#undef GATH
#undef ACCU
    __syncthreads();

    // GEMM phase: wave `wid` computes col-tile c = wid (16 rows x 16 cols)
    const int r  = lane & 15;       // A row
    const int kq = lane >> 4;       // k-quarter
    const f16x8 af0 = *(const f16x8*)&sA[r][0 * 32 + kq * 8];
    const f16x8 af1 = *(const f16x8*)&sA[r][1 * 32 + kq * 8];
    const f16x8 af2 = *(const f16x8*)&sA[r][2 * 32 + kq * 8];
    const f16x8 af3 = *(const f16x8*)&sA[r][3 * 32 + kq * 8];
    const f16x8 af4 = *(const f16x8*)&sA[r][4 * 32 + kq * 8];
    const f16x8 af5 = *(const f16x8*)&sA[r][5 * 32 + kq * 8];
    const f16x8 af6 = *(const f16x8*)&sA[r][6 * 32 + kq * 8];
    const f16x8 af7 = *(const f16x8*)&sA[r][7 * 32 + kq * 8];
    const f16x8 bf0 = *(const f16x8*)&wfrag[(size_t)((0 * 4 + wid) * 64 + lane) * 8];
    const f16x8 bf1 = *(const f16x8*)&wfrag[(size_t)((1 * 4 + wid) * 64 + lane) * 8];
    const f16x8 bf2 = *(const f16x8*)&wfrag[(size_t)((2 * 4 + wid) * 64 + lane) * 8];
    const f16x8 bf3 = *(const f16x8*)&wfrag[(size_t)((3 * 4 + wid) * 64 + lane) * 8];
    const f16x8 bf4 = *(const f16x8*)&wfrag[(size_t)((4 * 4 + wid) * 64 + lane) * 8];
    const f16x8 bf5 = *(const f16x8*)&wfrag[(size_t)((5 * 4 + wid) * 64 + lane) * 8];
    const f16x8 bf6 = *(const f16x8*)&wfrag[(size_t)((6 * 4 + wid) * 64 + lane) * 8];
    const f16x8 bf7 = *(const f16x8*)&wfrag[(size_t)((7 * 4 + wid) * 64 + lane) * 8];

    f32x4 acc = {0.f, 0.f, 0.f, 0.f};
    acc = MFMA16(af0, bf0, acc);
    acc = MFMA16(af1, bf1, acc);
    acc = MFMA16(af2, bf2, acc);
    acc = MFMA16(af3, bf3, acc);
    acc = MFMA16(af4, bf4, acc);
    acc = MFMA16(af5, bf5, acc);
    acc = MFMA16(af6, bf6, acc);
    acc = MFMA16(af7, bf7, acc);

    // epilogue: D col=lane&15, row=(lane>>4)*4+reg
    const int col = wid * 16 + r;
    const float bv = bias[col];
    const int lrow0 = (lane >> 4) * 4;
#pragma unroll
    for (int q = 0; q < 4; ++q) {
        const int lr = lrow0 + q;
        const float res = (float)sA[lr][192 + col];
        const float v = acc[q] + bv + res;
        out[(size_t)(blockIdx.x * 16 + lr) * 64 + col] = v / (1.0f + expf(-v));
    }
}

extern "C" void kernel_launch(void* const* d_in, const int* in_sizes, int n_in,
                              void* d_out, int out_size, void* d_ws, size_t ws_size,
                              hipStream_t stream) {
    const float* x     = (const float*)d_in[0];
    const int*   ei    = (const int*)d_in[1];
    const float* ea    = (const float*)d_in[2];
    const float* g     = (const float*)d_in[3];
    const float* mu    = (const float*)d_in[4];
    const float* sigma = (const float*)d_in[5];
    const float* root  = (const float*)d_in[6];
    const float* bias  = (const float*)d_in[7];
    float* out = (float*)d_out;

    char* ws = (char*)d_ws;
    const size_t xh_bytes     = (size_t)N_NODES * 64 * sizeof(_Float16);  //  6.4 MB
    const size_t packed_bytes = (size_t)N_EDGES * sizeof(unsigned);       //  3.2 MB
    const size_t rank_bytes   = (size_t)N_EDGES * sizeof(int);            //  3.2 MB
    const size_t wfrag_bytes  = (size_t)2048 * 8 * sizeof(_Float16);      //  32 KB
    _Float16* xh     = (_Float16*)ws;
    unsigned* packed = (unsigned*)(ws + xh_bytes);
    int*      rank   = (int*)(ws + xh_bytes + packed_bytes);
    _Float16* wfrag  = (_Float16*)(ws + xh_bytes + packed_bytes + rank_bytes);
    int* counts = (int*)(ws + xh_bytes + packed_bytes + rank_bytes + wfrag_bytes);
    int* off    = counts + N_NODES;           // N_NODES+1 entries
    int* bsum   = off + N_NODES + 1;

    xh_kernel<<<(N_NODES * 16 + 255) / 256, 256, 0, stream>>>(x, xh, counts, g, root, wfrag);
    hist_kernel<<<(N_EDGES + 255) / 256, 256, 0, stream>>>(ei, counts, rank);
    scanA_kernel<<<NB_SCAN, 256, 0, stream>>>(counts, bsum);
    scanC_kernel<<<NB_SCAN, 256, 0, stream>>>(counts, bsum, off);
    scatter_kernel<<<(N_EDGES + 255) / 256, 256, 0, stream>>>(ei, ea, off, rank, packed);
    agg_gemm_kernel<<<N_NODES / 16, 256, 0, stream>>>(xh, packed, off, mu, sigma, wfrag, bias, out);
}